// Round 3
// baseline (1387.257 us; speedup 1.0000x reference)
//
#include <hip/hip_runtime.h>
#include <hip/hip_bf16.h>
#include <math.h>

#define IGNORE_INDEX (-100)
#define BETA 0.1f

// Problem constants (B=8, S=512, H=4096, V=32000)
constexpr int Mdim = 8 * 512;   // 4096 tokens
constexpr int Kdim = 4096;      // hidden
constexpr int Ndim = 32000;     // vocab

// fp8 GEMM geometry: 256x256 tile, 8 waves (2M x 4N), per-wave 128x64, BK=128 (one mfma-K)
constexpr int BM2 = 256, BN2 = 256, BK8 = 128;
constexpr int MT2 = Mdim / BM2;   // 16 m-tiles
constexpr int NT2 = Ndim / BN2;   // 125 n-tiles
constexpr int NTILES = Kdim / BK8; // 32 K-tiles

// fallback geometry
constexpr int BM = 128, BN = 128;
constexpr int MT = Mdim / BM;   // 32
constexpr int NT = Ndim / BN;   // 250

typedef __bf16 bf16x8 __attribute__((ext_vector_type(8)));
typedef __bf16 bf16x4 __attribute__((ext_vector_type(4)));
typedef float  floatx4 __attribute__((ext_vector_type(4)));
typedef int    v8i __attribute__((ext_vector_type(8)));
typedef int    v4i __attribute__((ext_vector_type(4)));

#define GPTR(p) ((const __attribute__((address_space(1))) void*)(p))
#define LPTR(p) ((__attribute__((address_space(3))) void*)(p))

// fp32 -> fp8 e4m3 via HW v_cvt_pk_fp8_f32. Lane-contiguous float4 grid-stride.
// Single launch covers both x and w ranges.
__global__ void cvt_f32_fp8(const float4* __restrict__ xs, uint* __restrict__ xd, long nx4,
                            const float4* __restrict__ ws, uint* __restrict__ wd, long nw4) {
    long stride = (long)gridDim.x * blockDim.x;
    long ntot = nx4 + nw4;
    for (long i = (long)blockIdx.x * blockDim.x + threadIdx.x; i < ntot; i += stride) {
        const float4* s; uint* d; long j;
        if (i < nx4) { s = xs; d = xd; j = i; } else { s = ws; d = wd; j = i - nx4; }
        float4 a = s[j];
        int r = __builtin_amdgcn_cvt_pk_fp8_f32(a.x, a.y, 0, false);
        r     = __builtin_amdgcn_cvt_pk_fp8_f32(a.z, a.w, r, true);
        d[j] = (uint)r;
    }
}

// MX-fp8 GEMM (unit E8M0 scales) + fused softmax-stat epilogue.
// 256x256 tile, 8 waves, per-wave 128x64 output (8x4 16x16 frags).
// T3+T4 schedule (m201 template shape): 4 phases per K-tile, each
//   { ds_read this phase's operands ; issue stage loads ; s_barrier ;
//     lgkmcnt(0) ; setprio(1) 8xMFMA setprio(0) ; s_barrier }
// Raw s_barrier (NO implicit vmcnt drain) keeps stage loads in flight across
// phases; the ONLY vmcnt(0) is at the tile boundary, where in-flight = the
// t+1 loads issued >=2 phases earlier (drain nearly free).
// Cross-wave safety: every wave's slot-s ds_reads retire at its phase-3
// lgkmcnt(0); the boundary barrier therefore certifies (a) all reads of slot s
// retired -> t+2 staging into s is safe next tile, (b) all t+1 stage loads
// retired -> slot s^1 readable.
// LDS XOR-swizzle (verified): LDS[row][c] = G[row][c ^ (row&7)] in 16B chunks,
// applied on the GLOBAL address so global_load_lds's linear dest stays legal.
__global__ __launch_bounds__(512, 2)
void dpo_gemm_fp8(const unsigned char* __restrict__ x8, const unsigned char* __restrict__ w8,
                  const int* __restrict__ target,
                  float* __restrict__ sumexp, float* __restrict__ sumlog,
                  float* __restrict__ tgtlogit)
{
    __shared__ unsigned char Alds[2 * BM2 * BK8];   // 64 KB
    __shared__ unsigned char Blds[2 * BN2 * BK8];   // 64 KB
    __shared__ int tgt_s[BM2];

    const int tid  = threadIdx.x;
    const int lane = tid & 63;
    const int wid  = tid >> 6;        // 0..7
    const int wr   = wid >> 2;        // wave M-half (0..1) -> rows wr*128
    const int wc   = wid & 3;         // wave N-quarter (0..3) -> cols wc*64

    // XCD-aware bijective swizzle (nwg=2000 = 8*250), m-fastest for weight-strip locality.
    const int bid = blockIdx.x;
    const int swz = (bid & 7) * (MT2 * NT2 / 8) + (bid >> 3);
    const int m0  = (swz & (MT2 - 1)) * BM2;
    const int n0  = (swz / MT2) * BN2;

    if (tid < BM2) tgt_s[tid] = target[m0 + tid];

    floatx4 acc[8][4] = {};

    const int qr = lane >> 4;   // quad 0..3 (k-group)
    const int cr = lane & 15;   // row-in-frag

    // Staging geometry: wave w covers rows w*32..w*32+31 over 4 issues (8 rows each).
    // lane l -> row = base + (l>>3), global chunk = (l&7)^(l>>3)  [row&7 == l>>3].
    const int srow   = lane >> 3;
    const int schunk = (lane & 7) ^ srow;
    const unsigned char* xg = x8 + (size_t)(m0 + wid * 32 + srow) * Kdim + schunk * 16;
    const unsigned char* wg = w8 + (size_t)(n0 + wid * 32 + srow) * Kdim + schunk * 16;
    const int stage_base = wid * 32 * BK8;   // byte offset of this wave's 4KB region

    // Prologue: stage K-tile 0 into slot 0, drain, sync.
    #pragma unroll
    for (int i = 0; i < 4; ++i) {
        __builtin_amdgcn_global_load_lds(GPTR(xg + (size_t)i * 8 * Kdim),
                                         LPTR(Alds + stage_base + i * 1024), 16, 0, 0);
        __builtin_amdgcn_global_load_lds(GPTR(wg + (size_t)i * 8 * Kdim),
                                         LPTR(Blds + stage_base + i * 1024), 16, 0, 0);
    }
    asm volatile("s_waitcnt vmcnt(0)" ::: "memory");
    __builtin_amdgcn_s_barrier();
    asm volatile("" ::: "memory");

    // Fragment chunk swizzle: global k-chunks 2q,2q+1 live at LDS chunks (2q)^s,(2q+1)^s,
    // s = row&7 = cr&7.
    const int sx = cr & 7;
    const int c0 = (2 * qr) ^ sx;
    const int c1 = (2 * qr + 1) ^ sx;

    for (int t = 0; t < NTILES; ++t) {
        const unsigned char* Asl = Alds + (t & 1) * (BM2 * BK8);
        const unsigned char* Bsl = Blds + (t & 1) * (BN2 * BK8);
        unsigned char* Asn = (unsigned char*)Alds + ((t + 1) & 1) * (BM2 * BK8) + stage_base;
        unsigned char* Bsn = (unsigned char*)Blds + ((t + 1) & 1) * (BN2 * BK8) + stage_base;
        const bool pf = (t + 1 < NTILES);

        v8i bfrag[4], af0, af1;

        // ================= phase 0: B-frags + A01 ; stage A(t+1) ; mfma acc[0..1]
        #pragma unroll
        for (int ni = 0; ni < 4; ++ni) {
            const int base = (wc * 64 + ni * 16 + cr) * BK8;
            v4i lo = *(const v4i*)&Bsl[base + c0 * 16];
            v4i hi = *(const v4i*)&Bsl[base + c1 * 16];
            bfrag[ni] = __builtin_shufflevector(lo, hi, 0, 1, 2, 3, 4, 5, 6, 7);
        }
        {
            const int ba = (wr * 128 + 0 * 16 + cr) * BK8;
            v4i lo = *(const v4i*)&Asl[ba + c0 * 16];
            v4i hi = *(const v4i*)&Asl[ba + c1 * 16];
            af0 = __builtin_shufflevector(lo, hi, 0, 1, 2, 3, 4, 5, 6, 7);
            const int bb = (wr * 128 + 1 * 16 + cr) * BK8;
            v4i lo2 = *(const v4i*)&Asl[bb + c0 * 16];
            v4i hi2 = *(const v4i*)&Asl[bb + c1 * 16];
            af1 = __builtin_shufflevector(lo2, hi2, 0, 1, 2, 3, 4, 5, 6, 7);
        }
        if (pf) {
            const unsigned char* g = xg + (size_t)(t + 1) * BK8;
            #pragma unroll
            for (int i = 0; i < 4; ++i)
                __builtin_amdgcn_global_load_lds(GPTR(g + (size_t)i * 8 * Kdim),
                                                 LPTR(Asn + i * 1024), 16, 0, 0);
        }
        __builtin_amdgcn_s_barrier();
        asm volatile("s_waitcnt lgkmcnt(0)" ::: "memory");
        __builtin_amdgcn_sched_barrier(0);
        __builtin_amdgcn_s_setprio(1);
        #pragma unroll
        for (int ni = 0; ni < 4; ++ni) {
            acc[0][ni] = __builtin_amdgcn_mfma_scale_f32_16x16x128_f8f6f4(
                af0, bfrag[ni], acc[0][ni], 0, 0, 0, 0x7F7F7F7F, 0, 0x7F7F7F7F);
            acc[1][ni] = __builtin_amdgcn_mfma_scale_f32_16x16x128_f8f6f4(
                af1, bfrag[ni], acc[1][ni], 0, 0, 0, 0x7F7F7F7F, 0, 0x7F7F7F7F);
        }
        __builtin_amdgcn_s_setprio(0);
        __builtin_amdgcn_sched_barrier(0);
        __builtin_amdgcn_s_barrier();
        asm volatile("" ::: "memory");

        // ================= phase 1: A23 ; stage B(t+1) ; mfma acc[2..3]
        {
            const int ba = (wr * 128 + 2 * 16 + cr) * BK8;
            v4i lo = *(const v4i*)&Asl[ba + c0 * 16];
            v4i hi = *(const v4i*)&Asl[ba + c1 * 16];
            af0 = __builtin_shufflevector(lo, hi, 0, 1, 2, 3, 4, 5, 6, 7);
            const int bb = (wr * 128 + 3 * 16 + cr) * BK8;
            v4i lo2 = *(const v4i*)&Asl[bb + c0 * 16];
            v4i hi2 = *(const v4i*)&Asl[bb + c1 * 16];
            af1 = __builtin_shufflevector(lo2, hi2, 0, 1, 2, 3, 4, 5, 6, 7);
        }
        if (pf) {
            const unsigned char* g = wg + (size_t)(t + 1) * BK8;
            #pragma unroll
            for (int i = 0; i < 4; ++i)
                __builtin_amdgcn_global_load_lds(GPTR(g + (size_t)i * 8 * Kdim),
                                                 LPTR(Bsn + i * 1024), 16, 0, 0);
        }
        __builtin_amdgcn_s_barrier();
        asm volatile("s_waitcnt lgkmcnt(0)" ::: "memory");
        __builtin_amdgcn_sched_barrier(0);
        __builtin_amdgcn_s_setprio(1);
        #pragma unroll
        for (int ni = 0; ni < 4; ++ni) {
            acc[2][ni] = __builtin_amdgcn_mfma_scale_f32_16x16x128_f8f6f4(
                af0, bfrag[ni], acc[2][ni], 0, 0, 0, 0x7F7F7F7F, 0, 0x7F7F7F7F);
            acc[3][ni] = __builtin_amdgcn_mfma_scale_f32_16x16x128_f8f6f4(
                af1, bfrag[ni], acc[3][ni], 0, 0, 0, 0x7F7F7F7F, 0, 0x7F7F7F7F);
        }
        __builtin_amdgcn_s_setprio(0);
        __builtin_amdgcn_sched_barrier(0);
        __builtin_amdgcn_s_barrier();
        asm volatile("" ::: "memory");

        // ================= phase 2: A45 ; mfma acc[4..5]
        {
            const int ba = (wr * 128 + 4 * 16 + cr) * BK8;
            v4i lo = *(const v4i*)&Asl[ba + c0 * 16];
            v4i hi = *(const v4i*)&Asl[ba + c1 * 16];
            af0 = __builtin_shufflevector(lo, hi, 0, 1, 2, 3, 4, 5, 6, 7);
            const int bb = (wr * 128 + 5 * 16 + cr) * BK8;
            v4i lo2 = *(const v4i*)&Asl[bb + c0 * 16];
            v4i hi2 = *(const v4i*)&Asl[bb + c1 * 16];
            af1 = __builtin_shufflevector(lo2, hi2, 0, 1, 2, 3, 4, 5, 6, 7);
        }
        __builtin_amdgcn_s_barrier();
        asm volatile("s_waitcnt lgkmcnt(0)" ::: "memory");
        __builtin_amdgcn_sched_barrier(0);
        __builtin_amdgcn_s_setprio(1);
        #pragma unroll
        for (int ni = 0; ni < 4; ++ni) {
            acc[4][ni] = __builtin_amdgcn_mfma_scale_f32_16x16x128_f8f6f4(
                af0, bfrag[ni], acc[4][ni], 0, 0, 0, 0x7F7F7F7F, 0, 0x7F7F7F7F);
            acc[5][ni] = __builtin_amdgcn_mfma_scale_f32_16x16x128_f8f6f4(
                af1, bfrag[ni], acc[5][ni], 0, 0, 0, 0x7F7F7F7F, 0, 0x7F7F7F7F);
        }
        __builtin_amdgcn_s_setprio(0);
        __builtin_amdgcn_sched_barrier(0);
        __builtin_amdgcn_s_barrier();
        asm volatile("" ::: "memory");

        // ================= phase 3: A67 ; mfma acc[6..7] ; boundary vmcnt(0)
        {
            const int ba = (wr * 128 + 6 * 16 + cr) * BK8;
            v4i lo = *(const v4i*)&Asl[ba + c0 * 16];
            v4i hi = *(const v4i*)&Asl[ba + c1 * 16];
            af0 = __builtin_shufflevector(lo, hi, 0, 1, 2, 3, 4, 5, 6, 7);
            const int bb = (wr * 128 + 7 * 16 + cr) * BK8;
            v4i lo2 = *(const v4i*)&Asl[bb + c0 * 16];
            v4i hi2 = *(const v4i*)&Asl[bb + c1 * 16];
            af1 = __builtin_shufflevector(lo2, hi2, 0, 1, 2, 3, 4, 5, 6, 7);
        }
        __builtin_amdgcn_s_barrier();
        asm volatile("s_waitcnt lgkmcnt(0)" ::: "memory");
        __builtin_amdgcn_sched_barrier(0);
        __builtin_amdgcn_s_setprio(1);
        #pragma unroll
        for (int ni = 0; ni < 4; ++ni) {
            acc[6][ni] = __builtin_amdgcn_mfma_scale_f32_16x16x128_f8f6f4(
                af0, bfrag[ni], acc[6][ni], 0, 0, 0, 0x7F7F7F7F, 0, 0x7F7F7F7F);
            acc[7][ni] = __builtin_amdgcn_mfma_scale_f32_16x16x128_f8f6f4(
                af1, bfrag[ni], acc[7][ni], 0, 0, 0, 0x7F7F7F7F, 0, 0x7F7F7F7F);
        }
        __builtin_amdgcn_s_setprio(0);
        __builtin_amdgcn_sched_barrier(0);
        // Boundary: the ONLY vmcnt drain per K-tile (t+1 loads issued >=2 phases ago).
        asm volatile("s_waitcnt vmcnt(0)" ::: "memory");
        __builtin_amdgcn_s_barrier();
        asm volatile("" ::: "memory");
    }

    // Epilogue: C/D layout col=lane&15, row=(lane>>4)*4+reg (shape-determined).
    #pragma unroll
    for (int mi8 = 0; mi8 < 8; ++mi8) {
        #pragma unroll
        for (int reg = 0; reg < 4; ++reg) {
            const int lrow = wr * 128 + mi8 * 16 + qr * 4 + reg;
            const int grow = m0 + lrow;
            const int t = tgt_s[lrow];
            float se = 0.f, sl = 0.f;
            #pragma unroll
            for (int ni = 0; ni < 4; ++ni) {
                float v = acc[mi8][ni][reg];
                int gcol = n0 + wc * 64 + ni * 16 + cr;
                if (t == gcol) tgtlogit[grow] = v;   // unique owner globally
                se += __expf(v);
                sl += v;
            }
            #pragma unroll
            for (int st = 1; st < 16; st <<= 1) {
                se += __shfl_xor(se, st, 64);
                sl += __shfl_xor(sl, st, 64);
            }
            if (cr == 0) {
                atomicAdd(&sumexp[grow], se);
                atomicAdd(&sumlog[grow], sl);
            }
        }
    }
}

// Fallback (ws too small): fp32-staged bf16 GEMM.
__global__ __launch_bounds__(256, 2)
void dpo_gemm_f32(const float* __restrict__ x, const float* __restrict__ w,
                  const int* __restrict__ target,
                  float* __restrict__ sumexp, float* __restrict__ sumlog,
                  float* __restrict__ tgtlogit)
{
    constexpr int BK = 32;
    constexpr int LDA = 40;
    __shared__ __bf16 As[BM * LDA];
    __shared__ __bf16 Bs[BN * LDA];
    __shared__ int tgt_s[BM];

    const int tid  = threadIdx.x;
    const int lane = tid & 63;
    const int wid  = tid >> 6;
    const int wm   = wid & 1;
    const int wn   = wid >> 1;
    const int bid  = blockIdx.x;
    const int m0   = (bid & (MT - 1)) * BM;
    const int n0   = (bid / MT) * BN;

    if (tid < BM) tgt_s[tid] = target[m0 + tid];

    floatx4 acc[4][4] = {};
    const int qr = lane >> 4;
    const int cr = lane & 15;

    for (int k0 = 0; k0 < Kdim; k0 += BK) {
        __syncthreads();
        #pragma unroll
        for (int i = 0; i < 4; ++i) {
            int idx = tid + i * 256;
            int row = idx >> 3;
            int c4  = (idx & 7) * 4;
            float4 v = *(const float4*)(x + (size_t)(m0 + row) * Kdim + k0 + c4);
            bf16x4 p;
            p[0] = (__bf16)v.x; p[1] = (__bf16)v.y; p[2] = (__bf16)v.z; p[3] = (__bf16)v.w;
            *(bf16x4*)&As[row * LDA + c4] = p;
        }
        #pragma unroll
        for (int i = 0; i < 4; ++i) {
            int idx = tid + i * 256;
            int row = idx >> 3;
            int c4  = (idx & 7) * 4;
            float4 v = *(const float4*)(w + (size_t)(n0 + row) * Kdim + k0 + c4);
            bf16x4 p;
            p[0] = (__bf16)v.x; p[1] = (__bf16)v.y; p[2] = (__bf16)v.z; p[3] = (__bf16)v.w;
            *(bf16x4*)&Bs[row * LDA + c4] = p;
        }
        __syncthreads();

        bf16x8 afrag[4], bfrag[4];
        #pragma unroll
        for (int mi = 0; mi < 4; ++mi)
            afrag[mi] = *(const bf16x8*)&As[(wm * 64 + mi * 16 + cr) * LDA + qr * 8];
        #pragma unroll
        for (int ni = 0; ni < 4; ++ni)
            bfrag[ni] = *(const bf16x8*)&Bs[(wn * 64 + ni * 16 + cr) * LDA + qr * 8];

        #pragma unroll
        for (int mi = 0; mi < 4; ++mi)
            #pragma unroll
            for (int ni = 0; ni < 4; ++ni)
                acc[mi][ni] = __builtin_amdgcn_mfma_f32_16x16x32_bf16(
                    afrag[mi], bfrag[ni], acc[mi][ni], 0, 0, 0);
    }

    #pragma unroll
    for (int mi = 0; mi < 4; ++mi) {
        #pragma unroll
        for (int reg = 0; reg < 4; ++reg) {
            const int lrow = wm * 64 + mi * 16 + qr * 4 + reg;
            const int grow = m0 + lrow;
            const int t = tgt_s[lrow];
            float se = 0.f, sl = 0.f;
            #pragma unroll
            for (int ni = 0; ni < 4; ++ni) {
                float v = acc[mi][ni][reg];
                int gcol = n0 + wn * 64 + ni * 16 + cr;
                if (t == gcol) tgtlogit[grow] = v;
                se += __expf(v);
                sl += v;
            }
            #pragma unroll
            for (int st = 1; st < 16; st <<= 1) {
                se += __shfl_xor(se, st, 64);
                sl += __shfl_xor(sl, st, 64);
            }
            if (cr == 0) {
                atomicAdd(&sumexp[grow], se);
                atomicAdd(&sumlog[grow], sl);
            }
        }
    }
}

// One block, 8 waves: wave w reduces sequence w (512 tokens).
__global__ void dpo_finalize(const float* __restrict__ sumexp,
                             const float* __restrict__ sumlog,
                             const float* __restrict__ tgtlogit,
                             const int* __restrict__ target,
                             float* __restrict__ out)
{
    __shared__ float s_logp[8], s_sl[8];
    const int lane = threadIdx.x & 63;
    const int w    = threadIdx.x >> 6;

    float lp = 0.f, cnt = 0.f, sl = 0.f;
    #pragma unroll
    for (int i = 0; i < 8; ++i) {
        int t  = w * 512 + i * 64 + lane;
        int tg = target[t];
        if (tg != IGNORE_INDEX) {
            lp  += tgtlogit[t] - logf(sumexp[t]);
            cnt += 1.f;
        }
        sl += sumlog[t];
    }
    #pragma unroll
    for (int s = 1; s < 64; s <<= 1) {
        lp  += __shfl_xor(lp, s, 64);
        cnt += __shfl_xor(cnt, s, 64);
        sl  += __shfl_xor(sl, s, 64);
    }
    if (lane == 0) { s_logp[w] = lp / cnt; s_sl[w] = sl; }
    __syncthreads();

    if (threadIdx.x == 0) {
        float cm = 0.f, rm = 0.f, loss = 0.f;
        for (int i = 0; i < 4; ++i) { cm += s_sl[i]; rm += s_sl[4 + i]; }
        const float denom = 4.f * 512.f * 32000.f;
        cm /= denom; rm /= denom;
        for (int i = 0; i < 4; ++i) {
            float d = BETA * (s_logp[i] - s_logp[4 + i]);
            float l = (d > 0.f) ? log1pf(expf(-d)) : (-d + log1pf(expf(d)));
            loss += l;
        }
        loss *= 0.25f;
        out[0] = loss;
        for (int i = 0; i < 4; ++i) out[1 + i] = s_logp[i];
        for (int i = 0; i < 4; ++i) out[5 + i] = s_logp[4 + i];
        out[9]  = cm;
        out[10] = rm;
        out[11] = 0.f;
    }
}

extern "C" void kernel_launch(void* const* d_in, const int* in_sizes, int n_in,
                              void* d_out, int out_size, void* d_ws, size_t ws_size,
                              hipStream_t stream) {
    const float* x      = (const float*)d_in[0];   // (8,512,4096) fp32
    const float* wgt    = (const float*)d_in[1];   // (32000,4096) fp32
    const int*   target = (const int*)d_in[2];     // (8,512) int32
    float* out = (float*)d_out;

    float* sumexp   = (float*)d_ws;
    float* sumlog   = sumexp + Mdim;
    float* tgtlogit = sumlog + Mdim;
    char*  base     = (char*)d_ws + 3 * Mdim * sizeof(float);
    unsigned char* x8 = (unsigned char*)base;
    unsigned char* w8 = x8 + (size_t)Mdim * Kdim;

    const size_t ws_needed = 3 * Mdim * sizeof(float)
                           + (size_t)Mdim * Kdim
                           + (size_t)Ndim * Kdim;

    hipMemsetAsync(d_ws, 0, 2 * Mdim * sizeof(float), stream);

    if (ws_size >= ws_needed) {
        const long nx4 = (long)Mdim * Kdim / 4;   //  4,194,304 float4s
        const long nw4 = (long)Ndim * Kdim / 4;   // 32,768,000 float4s
        cvt_f32_fp8<<<2048, 256, 0, stream>>>((const float4*)x, (uint*)x8, nx4,
                                              (const float4*)wgt, (uint*)w8, nw4);
        dpo_gemm_fp8<<<MT2 * NT2, 512, 0, stream>>>(x8, w8, target, sumexp, sumlog, tgtlogit);
    } else {
        dpo_gemm_f32<<<MT * NT, 256, 0, stream>>>(x, wgt, target, sumexp, sumlog, tgtlogit);
    }
    dpo_finalize<<<1, 512, 0, stream>>>(sumexp, sumlog, tgtlogit, target, out);
}